// Round 8
// baseline (234.749 us; speedup 1.0000x reference)
//
#include <hip/hip_runtime.h>
#include <hip/hip_fp16.h>
#include <cmath>

#define NLVL 16
#define QUAD_LVLS 13            // levels [0,13): row-pair quad entries (8B); [13,16): plain (4B)
#define TSIZE (1u << 19)
#define HMASK ((1u << 19) - 1u)
#define PRIME1 2654435761u
#define FSCALE 1024.0f          // 2^10: keeps |v|<=1e-4 in fp16-normal range
#define FINV   (1.0f/1024.0f)   // exact power of 2 -> no extra rounding

typedef float f32x4 __attribute__((ext_vector_type(4)));
typedef unsigned int       u32;
typedef unsigned long long u64;

struct Params {
    float rf[NLVL];
    int   ri[NLVL];
    int   base[NLVL];     // u32 index of level's table inside ws
    int   stride[NLVL];   // entries per row = ri+2 (pad entry keeps edge loads in-bounds)
};

__device__ __forceinline__ float2 h2f(u32 u) {
    __half2 h; __builtin_memcpy(&h, &u, 4);
    return __half22float2(h);
}

__device__ __forceinline__ u32 packh(float2 v) {
    return (u32)__half_as_ushort(__float2half_rn(v.x * FSCALE))
         | ((u32)__half_as_ushort(__float2half_rn(v.y * FSCALE)) << 16);
}

// Pre-pass: hybrid dense table, sized to FIT the 4MiB per-XCD L2 (3.58 MB).
//  - levels 0..12: ROW-PAIR QUAD entries: entry(r,cx) = {cell(cx,r), cell(cx,r+1)}
//    (8B) -> full bilinear quad is ONE 16B load (one L2 line).
//  - levels 13..15 (the 3 largest, 84% of cells): plain 4B entries -> two 8B
//    row loads (two lines), but no duplication so the total stays L2-resident
//    (round 6's all-quad 5.7MB thrashed L2: FETCH 96MB, latency-bound).
__global__ __launch_bounds__(256) void build_dense_hyb(
    const float2* __restrict__ emb, u32* __restrict__ dense, Params p)
{
    const int l  = blockIdx.y;
    const int r  = blockIdx.x;
    const int ri = p.ri[l];
    if (r > ri) return;
    const u64* tab = (const u64*)(emb + (size_t)l * TSIZE);
    if (l < QUAD_LVLS) {
        const unsigned hy0 = (unsigned)r * PRIME1;
        const unsigned hy1 = (unsigned)min(r + 1, ri) * PRIME1;
        uint2* drow = (uint2*)(dense + p.base[l]) + (size_t)r * p.stride[l];
        for (int cx = threadIdx.x; cx <= ri; cx += 256) {
            u64 raw0 = __builtin_nontemporal_load(tab + (((unsigned)cx ^ hy0) & HMASK));
            u64 raw1 = __builtin_nontemporal_load(tab + (((unsigned)cx ^ hy1) & HMASK));
            float2 v0, v1;
            __builtin_memcpy(&v0, &raw0, 8);
            __builtin_memcpy(&v1, &raw1, 8);
            uint2 e; e.x = packh(v0); e.y = packh(v1);
            drow[cx] = e;
        }
    } else {
        const unsigned hy = (unsigned)r * PRIME1;
        u32* drow = dense + p.base[l] + (size_t)r * p.stride[l];
        for (int cx = threadIdx.x; cx <= ri; cx += 256) {
            u64 raw = __builtin_nontemporal_load(tab + (((unsigned)cx ^ hy) & HMASK));
            float2 v; __builtin_memcpy(&v, &raw, 8);
            drow[cx] = packh(v);
        }
    }
}

// Main: 13 quad-loads (1 line each) + 3x2 row-loads (2 lines each) = 11
// fine-level lines/point (vs 16 in r2), all issued up front for max MLP, on a
// 3.58MB L2-RESIDENT table. Write path = proven LDS transpose + nt coalesced
// stores (compulsory 132MB; per-thread cached line stores cost +77MB RFO, r5).
__global__ __launch_bounds__(256) void hash_embed_hyb(
    const float2* __restrict__ x,
    const u32*    __restrict__ dense,
    float*        __restrict__ out,
    Params p, int n)
{
    __shared__ float lds[8 * 512];   // 16 KiB, XOR-swizzled
    const int tid = threadIdx.x;
    const int i = blockIdx.x * 256 + tid;
    float2 xy = make_float2(0.f, 0.f);
    if (i < n) {
        u64 raw = __builtin_nontemporal_load((const u64*)(x + i));
        __builtin_memcpy(&xy, &raw, 8);
    }

    uint4 q[QUAD_LVLS];
    uint2 pa[NLVL - QUAD_LVLS], pb[NLVL - QUAD_LVLS];
    float w0v[NLVL], w1v[NLVL];
    u32 edgemask = 0;

    // phase 1: all gathers in flight (13 dwordx4 + 6 dwordx2)
    #pragma unroll
    for (int l = 0; l < QUAD_LVLS; ++l) {
        const float rf = p.rf[l];
        const int ri = p.ri[l];
        const float px = xy.x * rf, py = xy.y * rf;
        const float fx = floorf(px), fy = floorf(py);
        w0v[l] = px - fx;
        w1v[l] = py - fy;
        const int tx = (int)fx, ty = (int)fy;
        const int cx0 = min(tx, ri);
        const int cy0 = min(ty, ri);
        edgemask |= (u32)(cx0 == ri) << l;     // then cx1==cx0 (clip)
        const uint2* a = (const uint2*)(dense + p.base[l]) + cy0 * p.stride[l] + cx0;
        __builtin_memcpy(&q[l], a, 16);        // 8B-aligned dwordx4
    }
    #pragma unroll
    for (int m = 0; m < NLVL - QUAD_LVLS; ++m) {
        const int l = QUAD_LVLS + m;
        const float rf = p.rf[l];
        const int ri = p.ri[l];
        const float px = xy.x * rf, py = xy.y * rf;
        const float fx = floorf(px), fy = floorf(py);
        w0v[l] = px - fx;
        w1v[l] = py - fy;
        const int tx = (int)fx, ty = (int)fy;
        const int cx0 = min(tx, ri);
        const int cy0 = min(ty, ri);
        const int cy1 = min(ty + 1, ri);
        edgemask |= (u32)(cx0 == ri) << l;
        const u32* tab = dense + p.base[l];
        __builtin_memcpy(&pa[m], tab + cy0 * p.stride[l] + cx0, 8);
        __builtin_memcpy(&pb[m], tab + cy1 * p.stride[l] + cx0, 8);
    }
    __builtin_amdgcn_sched_barrier(0);         // don't sink loads into blends

    const long long total = (long long)n * 32;
    const long long base  = (long long)blockIdx.x * 8192;

    #pragma unroll
    for (int half = 0; half < 2; ++half) {
        if (half == 1) __syncthreads();        // half-0 readers done before overwrite
        #pragma unroll
        for (int j = 0; j < 8; ++j) {
            const int l = half * 8 + j;
            const float w0 = w0v[l], w1 = w1v[l];
            const float u0 = 1.f - w0, u1 = 1.f - w1;
            const bool ed = (edgemask >> l) & 1u;
            float2 e00, e01, e10, e11;
            if (l < QUAD_LVLS) {               // quad entry: x=e00 y=e10 z=e01 w=e11
                e00 = h2f(q[l].x);
                e10 = h2f(q[l].y);
                e01 = h2f(ed ? q[l].x : q[l].z);
                e11 = h2f(ed ? q[l].y : q[l].w);
            } else {                           // plain rows: a={e00,e01} b={e10,e11}
                const int m = l - QUAD_LVLS;
                e00 = h2f(pa[m].x);
                e01 = h2f(ed ? pa[m].x : pa[m].y);
                e10 = h2f(pb[m].x);
                e11 = h2f(ed ? pb[m].x : pb[m].y);
            }
            const float g0 = ((e00.x*u0 + e01.x*w0)*u1 + (e10.x*u0 + e11.x*w0)*w1) * FINV;
            const float g1 = ((e00.y*u0 + e01.y*w0)*u1 + (e10.y*u0 + e11.y*w0)*w1) * FINV;
            const int idx = j * 512 + ((2 * tid) ^ (j << 1));  // bank swizzle
            lds[idx]     = g0;
            lds[idx + 1] = g1;
        }
        __syncthreads();

        // coalesced nt write-out of this half (levels [half*8, half*8+8) are a
        // contiguous, 64B-aligned 16-float chunk per point)
        #pragma unroll
        for (int it = 0; it < 4; ++it) {
            const int f  = (it * 256 + tid) * 4;   // 0..4095
            const int p2 = f >> 4;                 // point within block
            const int kk = f & 15;                 // float within 16-float half
            const int lh = kk >> 1;                // {0,2,4,6}
            const long long g = base + (long long)p2 * 32 + half * 16 + kk;
            if (g < total) {
                const int s0 = lh * 512       + ((2 * p2) ^ (lh << 1));
                const int s1 = (lh + 1) * 512 + ((2 * p2) ^ ((lh + 1) << 1));
                f32x4 v;
                v.x = lds[s0]; v.y = lds[s0 + 1];
                v.z = lds[s1]; v.w = lds[s1 + 1];
                __builtin_nontemporal_store(v, (f32x4*)(out + g));
            }
        }
    }
}

// Fallback: direct f32 hash gathers, used only if ws is too small.
__global__ __launch_bounds__(256) void hash_embed_direct(
    const float2* __restrict__ x,
    const float2* __restrict__ emb,
    float* __restrict__ out,
    Params p, int n)
{
    __shared__ float2 lds[NLVL * 256];
    const int tid = threadIdx.x;
    const int i = blockIdx.x * 256 + tid;
    float2 xy = make_float2(0.f, 0.f);
    if (i < n) xy = x[i];

    #pragma unroll
    for (int half = 0; half < 2; ++half) {
        float2 f[32];
        float w0v[8], w1v[8];
        #pragma unroll
        for (int j = 0; j < 8; ++j) {
            const int l = half * 8 + j;
            const float rf = p.rf[l];
            const int ri = p.ri[l];
            const float px = xy.x * rf, py = xy.y * rf;
            const float fx = floorf(px), fy = floorf(py);
            w0v[j] = px - fx;
            w1v[j] = py - fy;
            const int tx = (int)fx, ty = (int)fy;
            const unsigned cx0 = (unsigned)min(tx, ri);
            const unsigned cy0 = (unsigned)min(ty, ri);
            const unsigned cx1 = (unsigned)min(tx + 1, ri);
            const unsigned cy1 = (unsigned)min(ty + 1, ri);
            const unsigned hy0 = cy0 * PRIME1;
            const unsigned hy1 = cy1 * PRIME1;
            const float2* tab = emb + (size_t)l * TSIZE;
            f[j*4+0] = tab[(cx0 ^ hy0) & HMASK];
            f[j*4+1] = tab[(cx1 ^ hy0) & HMASK];
            f[j*4+2] = tab[(cx0 ^ hy1) & HMASK];
            f[j*4+3] = tab[(cx1 ^ hy1) & HMASK];
        }
        #pragma unroll
        for (int j = 0; j < 8; ++j) {
            const int l = half * 8 + j;
            const float w0 = w0v[j], w1 = w1v[j];
            const float u0 = 1.f - w0, u1 = 1.f - w1;
            const float2 f0 = f[j*4+0], f1 = f[j*4+1], f2 = f[j*4+2], f3 = f[j*4+3];
            const float g0 = (f0.x*u0 + f1.x*w0)*u1 + (f2.x*u0 + f3.x*w0)*w1;
            const float g1 = (f0.y*u0 + f1.y*w0)*u1 + (f2.y*u0 + f3.y*w0)*w1;
            lds[l * 256 + tid] = make_float2(g0, g1);
        }
    }
    __syncthreads();

    const float* lf = (const float*)lds;
    const long long total = (long long)n * 32;
    const long long base = (long long)blockIdx.x * 8192;
    #pragma unroll
    for (int it = 0; it < 8; ++it) {
        const int k = (it * 256 + tid) * 4;
        if (base + k < total) {
            const int p2 = k >> 5;
            const int l0 = (k & 31) >> 1;
            float4 v;
            v.x = lf[(l0 * 256 + p2) * 2 + 0];
            v.y = lf[(l0 * 256 + p2) * 2 + 1];
            v.z = lf[((l0 + 1) * 256 + p2) * 2 + 0];
            v.w = lf[((l0 + 1) * 256 + p2) * 2 + 1];
            *(float4*)(out + base + k) = v;
        }
    }
}

extern "C" void kernel_launch(void* const* d_in, const int* in_sizes, int n_in,
                              void* d_out, int out_size, void* d_ws, size_t ws_size,
                              hipStream_t stream) {
    const float2* x = (const float2*)d_in[0];
    const float2* emb = (const float2*)d_in[1];
    float* out = (float*)d_out;
    const int n = in_sizes[0] / 2;

    // numpy-exact per-level resolutions (ulp-sensitive floors at l=3,6,9,...)
    Params p;
    int off = 0;   // u32 units; quad levels first (even increments -> 8B alignment)
    const double b = std::exp((std::log(512.0) - std::log(16.0)) / 15.0);
    for (int l = 0; l < NLVL; ++l) {
        const double r = std::floor(16.0 * std::pow(b, (double)l));
        p.rf[l] = (float)r;
        p.ri[l] = (int)r;
        p.stride[l] = p.ri[l] + 2;
        p.base[l] = off;
        const int cells = (p.ri[l] + 1) * (p.ri[l] + 2);
        off += (l < QUAD_LVLS) ? cells * 2 : cells;
    }
    const size_t need = (size_t)off * sizeof(u32);   // ~3.58 MiB (fits 4MiB XCD L2)

    const int grid = (n + 255) / 256;
    if (ws_size >= need) {
        build_dense_hyb<<<dim3(513, 16), 256, 0, stream>>>(emb, (u32*)d_ws, p);
        hash_embed_hyb<<<grid, 256, 0, stream>>>(x, (const u32*)d_ws, out, p, n);
    } else {
        hash_embed_direct<<<grid, 256, 0, stream>>>(x, emb, out, p, n);
    }
}

// Round 9
// 230.181 us; speedup vs baseline: 1.0198x; 1.0198x over previous
//
#include <hip/hip_runtime.h>
#include <hip/hip_fp16.h>
#include <cmath>

#define NLVL 16
#define QUAD_LVLS 13            // levels [0,13): row-pair quad entries (8B); [13,16): plain (4B)
#define TSIZE (1u << 19)
#define HMASK ((1u << 19) - 1u)
#define PRIME1 2654435761u
#define FSCALE 1024.0f          // 2^10: keeps |v|<=1e-4 in fp16-normal range
#define FINV   (1.0f/1024.0f)   // exact power of 2 -> no extra rounding

typedef float f32x4 __attribute__((ext_vector_type(4)));
typedef unsigned int       u32;
typedef unsigned long long u64;

struct Params {
    float rf[NLVL];
    int   ri[NLVL];
    int   base[NLVL];     // u32 index of level's table inside ws
    int   stride[NLVL];   // entries per row = ri+2 (pad entry keeps edge loads in-bounds)
};

__device__ __forceinline__ float2 h2f(u32 u) {
    __half2 h; __builtin_memcpy(&h, &u, 4);
    return __half22float2(h);
}

__device__ __forceinline__ u32 packh(float2 v) {
    return (u32)__half_as_ushort(__float2half_rn(v.x * FSCALE))
         | ((u32)__half_as_ushort(__float2half_rn(v.y * FSCALE)) << 16);
}

// Pre-pass: hybrid dense table, sized to FIT the 4MiB per-XCD L2 (3.58 MB).
//  - levels 0..12: ROW-PAIR QUAD entries entry(r,cx)={cell(cx,r),cell(cx,r+1)}
//    (8B) -> full bilinear quad is ONE 16B load (one L2 line).
//  - levels 13..15: plain 4B entries -> two 8B row loads (two lines), no
//    duplication so the total stays L2-resident (r6's 5.7MB all-quad thrashed:
//    FETCH 96MB; r8's 3.58MB hybrid restored FETCH to 22MB).
__global__ __launch_bounds__(256) void build_dense_hyb(
    const float2* __restrict__ emb, u32* __restrict__ dense, Params p)
{
    const int l  = blockIdx.y;
    const int r  = blockIdx.x;
    const int ri = p.ri[l];
    if (r > ri) return;
    const u64* tab = (const u64*)(emb + (size_t)l * TSIZE);
    if (l < QUAD_LVLS) {
        const unsigned hy0 = (unsigned)r * PRIME1;
        const unsigned hy1 = (unsigned)min(r + 1, ri) * PRIME1;
        uint2* drow = (uint2*)(dense + p.base[l]) + (size_t)r * p.stride[l];
        for (int cx = threadIdx.x; cx <= ri; cx += 256) {
            u64 raw0 = __builtin_nontemporal_load(tab + (((unsigned)cx ^ hy0) & HMASK));
            u64 raw1 = __builtin_nontemporal_load(tab + (((unsigned)cx ^ hy1) & HMASK));
            float2 v0, v1;
            __builtin_memcpy(&v0, &raw0, 8);
            __builtin_memcpy(&v1, &raw1, 8);
            uint2 e; e.x = packh(v0); e.y = packh(v1);
            drow[cx] = e;
        }
    } else {
        const unsigned hy = (unsigned)r * PRIME1;
        u32* drow = dense + p.base[l] + (size_t)r * p.stride[l];
        for (int cx = threadIdx.x; cx <= ri; cx += 256) {
            u64 raw = __builtin_nontemporal_load(tab + (((unsigned)cx ^ hy) & HMASK));
            float2 v; __builtin_memcpy(&v, &raw, 8);
            drow[cx] = packh(v);
        }
    }
}

// Main: hybrid-table gathers (11 fine lines/pt) on r2's TWO-HALF schedule.
// Only one half's payload (32 VGPR) is live at a time -> low VGPR -> high
// occupancy (r8's all-upfront issue held 19 loads live: 84 VGPR, 28% occ,
// and gather latency-hiding starved; r2's structure ran 48 VGPR @ 45%).
// Half-1's gathers issue BEFORE the half-0 barrier: latency hides under the
// half-0 write-out. Write path = proven LDS transpose + nt coalesced stores.
__global__ __launch_bounds__(256) void hash_embed_hyb2(
    const float2* __restrict__ x,
    const u32*    __restrict__ dense,
    float*        __restrict__ out,
    Params p, int n)
{
    __shared__ float lds[8 * 512];   // 16 KiB, XOR-swizzled
    const int tid = threadIdx.x;
    const int i = blockIdx.x * 256 + tid;
    float2 xy = make_float2(0.f, 0.f);
    if (i < n) {
        u64 raw = __builtin_nontemporal_load((const u64*)(x + i));
        __builtin_memcpy(&xy, &raw, 8);
    }

    const long long total = (long long)n * 32;
    const long long base  = (long long)blockIdx.x * 8192;

    #pragma unroll
    for (int half = 0; half < 2; ++half) {
        uint4 q[8];              // quad payload (h0: j=0..7; h1: j=0..4)
        uint2 pa[3], pb[3];      // plain payload (h1: j=5..7 -> m=j-5)
        float w0v[8], w1v[8];
        u32 edgemask = 0;

        // phase 1: this half's gathers in flight
        #pragma unroll
        for (int j = 0; j < 8; ++j) {
            const int l = half * 8 + j;
            const float rf = p.rf[l];
            const int ri = p.ri[l];
            const float px = xy.x * rf, py = xy.y * rf;
            const float fx = floorf(px), fy = floorf(py);
            w0v[j] = px - fx;
            w1v[j] = py - fy;
            const int tx = (int)fx, ty = (int)fy;
            const int cx0 = min(tx, ri);
            const int cy0 = min(ty, ri);
            edgemask |= (u32)(cx0 == ri) << j;       // then cx1==cx0 (clip)
            if (l < QUAD_LVLS) {
                const uint2* a = (const uint2*)(dense + p.base[l])
                               + cy0 * p.stride[l] + cx0;
                __builtin_memcpy(&q[j], a, 16);      // 8B-aligned dwordx4
            } else {
                const int m = j - 5;                 // h1 only: l=13..15
                const int cy1 = min(ty + 1, ri);
                const u32* tab = dense + p.base[l];
                __builtin_memcpy(&pa[m], tab + cy0 * p.stride[l] + cx0, 8);
                __builtin_memcpy(&pb[m], tab + cy1 * p.stride[l] + cx0, 8);
            }
        }

        // half 1 overwrites the LDS buffer: wait for half-0 write-out readers
        if (half == 1) __syncthreads();

        // phase 2: blend (reference fp32 order), stash to LDS
        #pragma unroll
        for (int j = 0; j < 8; ++j) {
            const int l = half * 8 + j;
            const float w0 = w0v[j], w1 = w1v[j];
            const float u0 = 1.f - w0, u1 = 1.f - w1;
            const bool ed = (edgemask >> j) & 1u;
            float2 e00, e01, e10, e11;
            if (l < QUAD_LVLS) {          // quad entry: x=e00 y=e10 z=e01 w=e11
                e00 = h2f(q[j].x);
                e10 = h2f(q[j].y);
                e01 = h2f(ed ? q[j].x : q[j].z);
                e11 = h2f(ed ? q[j].y : q[j].w);
            } else {                      // plain rows: a={e00,e01} b={e10,e11}
                const int m = j - 5;
                e00 = h2f(pa[m].x);
                e01 = h2f(ed ? pa[m].x : pa[m].y);
                e10 = h2f(pb[m].x);
                e11 = h2f(ed ? pb[m].x : pb[m].y);
            }
            const float g0 = ((e00.x*u0 + e01.x*w0)*u1 + (e10.x*u0 + e11.x*w0)*w1) * FINV;
            const float g1 = ((e00.y*u0 + e01.y*w0)*u1 + (e10.y*u0 + e11.y*w0)*w1) * FINV;
            const int idx = j * 512 + ((2 * tid) ^ (j << 1));  // bank swizzle
            lds[idx]     = g0;
            lds[idx + 1] = g1;
        }
        __syncthreads();

        // coalesced nt write-out of this half (levels [half*8, half*8+8) are a
        // contiguous, 64B-aligned 16-float chunk per point)
        #pragma unroll
        for (int it = 0; it < 4; ++it) {
            const int f  = (it * 256 + tid) * 4;   // 0..4095
            const int p2 = f >> 4;                 // point within block
            const int kk = f & 15;                 // float within 16-float half
            const int lh = kk >> 1;                // {0,2,4,6}
            const long long g = base + (long long)p2 * 32 + half * 16 + kk;
            if (g < total) {
                const int s0 = lh * 512       + ((2 * p2) ^ (lh << 1));
                const int s1 = (lh + 1) * 512 + ((2 * p2) ^ ((lh + 1) << 1));
                f32x4 v;
                v.x = lds[s0]; v.y = lds[s0 + 1];
                v.z = lds[s1]; v.w = lds[s1 + 1];
                __builtin_nontemporal_store(v, (f32x4*)(out + g));
            }
        }
    }
}

// Fallback: direct f32 hash gathers, used only if ws is too small.
__global__ __launch_bounds__(256) void hash_embed_direct(
    const float2* __restrict__ x,
    const float2* __restrict__ emb,
    float* __restrict__ out,
    Params p, int n)
{
    __shared__ float2 lds[NLVL * 256];
    const int tid = threadIdx.x;
    const int i = blockIdx.x * 256 + tid;
    float2 xy = make_float2(0.f, 0.f);
    if (i < n) xy = x[i];

    #pragma unroll
    for (int half = 0; half < 2; ++half) {
        float2 f[32];
        float w0v[8], w1v[8];
        #pragma unroll
        for (int j = 0; j < 8; ++j) {
            const int l = half * 8 + j;
            const float rf = p.rf[l];
            const int ri = p.ri[l];
            const float px = xy.x * rf, py = xy.y * rf;
            const float fx = floorf(px), fy = floorf(py);
            w0v[j] = px - fx;
            w1v[j] = py - fy;
            const int tx = (int)fx, ty = (int)fy;
            const unsigned cx0 = (unsigned)min(tx, ri);
            const unsigned cy0 = (unsigned)min(ty, ri);
            const unsigned cx1 = (unsigned)min(tx + 1, ri);
            const unsigned cy1 = (unsigned)min(ty + 1, ri);
            const unsigned hy0 = cy0 * PRIME1;
            const unsigned hy1 = cy1 * PRIME1;
            const float2* tab = emb + (size_t)l * TSIZE;
            f[j*4+0] = tab[(cx0 ^ hy0) & HMASK];
            f[j*4+1] = tab[(cx1 ^ hy0) & HMASK];
            f[j*4+2] = tab[(cx0 ^ hy1) & HMASK];
            f[j*4+3] = tab[(cx1 ^ hy1) & HMASK];
        }
        #pragma unroll
        for (int j = 0; j < 8; ++j) {
            const int l = half * 8 + j;
            const float w0 = w0v[j], w1 = w1v[j];
            const float u0 = 1.f - w0, u1 = 1.f - w1;
            const float2 f0 = f[j*4+0], f1 = f[j*4+1], f2 = f[j*4+2], f3 = f[j*4+3];
            const float g0 = (f0.x*u0 + f1.x*w0)*u1 + (f2.x*u0 + f3.x*w0)*w1;
            const float g1 = (f0.y*u0 + f1.y*w0)*u1 + (f2.y*u0 + f3.y*w0)*w1;
            lds[l * 256 + tid] = make_float2(g0, g1);
        }
    }
    __syncthreads();

    const float* lf = (const float*)lds;
    const long long total = (long long)n * 32;
    const long long base = (long long)blockIdx.x * 8192;
    #pragma unroll
    for (int it = 0; it < 8; ++it) {
        const int k = (it * 256 + tid) * 4;
        if (base + k < total) {
            const int p2 = k >> 5;
            const int l0 = (k & 31) >> 1;
            float4 v;
            v.x = lf[(l0 * 256 + p2) * 2 + 0];
            v.y = lf[(l0 * 256 + p2) * 2 + 1];
            v.z = lf[((l0 + 1) * 256 + p2) * 2 + 0];
            v.w = lf[((l0 + 1) * 256 + p2) * 2 + 1];
            *(float4*)(out + base + k) = v;
        }
    }
}

extern "C" void kernel_launch(void* const* d_in, const int* in_sizes, int n_in,
                              void* d_out, int out_size, void* d_ws, size_t ws_size,
                              hipStream_t stream) {
    const float2* x = (const float2*)d_in[0];
    const float2* emb = (const float2*)d_in[1];
    float* out = (float*)d_out;
    const int n = in_sizes[0] / 2;

    // numpy-exact per-level resolutions (ulp-sensitive floors at l=3,6,9,...)
    Params p;
    int off = 0;   // u32 units; quad levels have even bases (8B alignment)
    const double b = std::exp((std::log(512.0) - std::log(16.0)) / 15.0);
    for (int l = 0; l < NLVL; ++l) {
        const double r = std::floor(16.0 * std::pow(b, (double)l));
        p.rf[l] = (float)r;
        p.ri[l] = (int)r;
        p.stride[l] = p.ri[l] + 2;
        p.base[l] = off;
        const int cells = (p.ri[l] + 1) * (p.ri[l] + 2);
        off += (l < QUAD_LVLS) ? cells * 2 : cells;
    }
    const size_t need = (size_t)off * sizeof(u32);   // ~3.58 MiB (fits 4MiB XCD L2)

    const int grid = (n + 255) / 256;
    if (ws_size >= need) {
        build_dense_hyb<<<dim3(513, 16), 256, 0, stream>>>(emb, (u32*)d_ws, p);
        hash_embed_hyb2<<<grid, 256, 0, stream>>>(x, (const u32*)d_ws, out, p, n);
    } else {
        hash_embed_direct<<<grid, 256, 0, stream>>>(x, emb, out, p, n);
    }
}